// Round 2
// 158.887 us; speedup vs baseline: 1.0101x; 1.0101x over previous
//
#include <hip/hip_runtime.h>
#include <hip/hip_fp16.h>

#define N 1024
#define D 128

// ---------------- proj: Q,K (f32) + Ah,Bh (f16) = z@{Wq,Wk,W1a,W1b} ----------------
__global__ __launch_bounds__(256) void proj_kernel(
    const float* __restrict__ z,
    const float* __restrict__ Wq, const float* __restrict__ bq,
    const float* __restrict__ Wk, const float* __restrict__ bk,
    const float* __restrict__ W1, const float* __restrict__ b1,
    float* __restrict__ Q, float* __restrict__ Kx,
    __half* __restrict__ Ah, __half* __restrict__ Bh)
{
    const int d  = threadIdx.x & (D - 1);
    const int h  = threadIdx.x >> 7;              // wave-uniform: 0 -> Q/K, 1 -> A/B
    const int r0 = blockIdx.x * 8;
    const float* __restrict__ Wa = h ? W1           : Wq;
    const float* __restrict__ Wb = h ? (W1 + D * D) : Wk;

    float acc0[8] = {0,0,0,0,0,0,0,0};
    float acc1[8] = {0,0,0,0,0,0,0,0};

    for (int c = 0; c < D / 4; ++c) {
        float4 zr[8];
#pragma unroll
        for (int r = 0; r < 8; ++r)
            zr[r] = *(const float4*)&z[(r0 + r) * D + c * 4];
#pragma unroll
        for (int q = 0; q < 4; ++q) {
            const int k = c * 4 + q;
            const float wa = Wa[k * D + d];
            const float wb = Wb[k * D + d];
#pragma unroll
            for (int r = 0; r < 8; ++r) {
                const float zv = (q == 0) ? zr[r].x : (q == 1) ? zr[r].y : (q == 2) ? zr[r].z : zr[r].w;
                acc0[r] = fmaf(zv, wa, acc0[r]);
                acc1[r] = fmaf(zv, wb, acc1[r]);
            }
        }
    }
    if (h == 0) {
        const float c0 = bq[d], c1 = bk[d];
        const float scale = 0.08838834764831845f;   // 1/sqrt(128), folded into Q
#pragma unroll
        for (int r = 0; r < 8; ++r) {
            Q [(r0 + r) * D + d] = (acc0[r] + c0) * scale;
            Kx[(r0 + r) * D + d] = acc1[r] + c1;
        }
    } else {
        const float c0 = b1[d];
#pragma unroll
        for (int r = 0; r < 8; ++r) {
            Ah[(r0 + r) * D + d] = __float2half(acc0[r] + c0);   // b1 folded
            Bh[(r0 + r) * D + d] = __float2half(acc1[r]);
        }
    }
}

// ---------------- scores: S = (Q K^T) * exp(-dist), 32x32 tile (known-good) ----------------
__global__ __launch_bounds__(256) void score_kernel(
    const float* __restrict__ Q, const float* __restrict__ Kx,
    const float* __restrict__ dist, float* __restrict__ S)
{
    __shared__ float Qs[32 * 33 * 4];
    __shared__ float Ks[32 * 33 * 4];
    const int tid = threadIdx.x;
    const int bi = blockIdx.y * 32, bj = blockIdx.x * 32;
    const int tx = tid & 15, ty = tid >> 4;

#pragma unroll
    for (int t = 0; t < 4; ++t) {
        const int e = t * 256 + tid;
        const int row = e >> 5, c = e & 31;
        *(float4*)&Qs[(row * 33 + c) * 4] = *(const float4*)&Q [(size_t)(bi + row) * D + c * 4];
        *(float4*)&Ks[(row * 33 + c) * 4] = *(const float4*)&Kx[(size_t)(bj + row) * D + c * 4];
    }
    __syncthreads();

    const float4* Qs4 = (const float4*)Qs;
    const float4* Ks4 = (const float4*)Ks;
    float a00 = 0.f, a01 = 0.f, a10 = 0.f, a11 = 0.f;

#pragma unroll 4
    for (int c = 0; c < 32; ++c) {
        const float4 q0 = Qs4[ty * 33 + c];
        const float4 q1 = Qs4[(ty + 16) * 33 + c];
        const float4 k0 = Ks4[tx * 33 + c];
        const float4 k1 = Ks4[(tx + 16) * 33 + c];
        a00 = fmaf(q0.x, k0.x, a00); a00 = fmaf(q0.y, k0.y, a00); a00 = fmaf(q0.z, k0.z, a00); a00 = fmaf(q0.w, k0.w, a00);
        a01 = fmaf(q0.x, k1.x, a01); a01 = fmaf(q0.y, k1.y, a01); a01 = fmaf(q0.z, k1.z, a01); a01 = fmaf(q0.w, k1.w, a01);
        a10 = fmaf(q1.x, k0.x, a10); a10 = fmaf(q1.y, k0.y, a10); a10 = fmaf(q1.z, k0.z, a10); a10 = fmaf(q1.w, k0.w, a10);
        a11 = fmaf(q1.x, k1.x, a11); a11 = fmaf(q1.y, k1.y, a11); a11 = fmaf(q1.z, k1.z, a11); a11 = fmaf(q1.w, k1.w, a11);
    }

    const int i0 = bi + ty, i1 = bi + ty + 16;
    const int j0 = bj + tx, j1 = bj + tx + 16;
    S[(size_t)i0 * N + j0] = a00 * __expf(-dist[(size_t)i0 * N + j0]);
    S[(size_t)i0 * N + j1] = a01 * __expf(-dist[(size_t)i0 * N + j1]);
    S[(size_t)i1 * N + j0] = a10 * __expf(-dist[(size_t)i1 * N + j0]);
    S[(size_t)i1 * N + j1] = a11 * __expf(-dist[(size_t)i1 * N + j1]);
}

// ---------------- softmax + top-32 per row; one wave per row (known-good) ----------------
__global__ __launch_bounds__(256) void topk_kernel(float* buf)
{
    const int lane = threadIdx.x & 63;
    const int row  = blockIdx.x * 4 + (threadIdx.x >> 6);
    float* sr = buf + (size_t)row * N;

    float v[16];
#pragma unroll
    for (int c = 0; c < 4; ++c) {
        const float4 f = *(const float4*)&sr[(c * 64 + lane) * 4];
        v[c * 4 + 0] = f.x; v[c * 4 + 1] = f.y; v[c * 4 + 2] = f.z; v[c * 4 + 3] = f.w;
    }
    float m = v[0];
#pragma unroll
    for (int e = 1; e < 16; ++e) m = fmaxf(m, v[e]);
#pragma unroll
    for (int off = 1; off < 64; off <<= 1) m = fmaxf(m, __shfl_xor(m, off));
    float sum = 0.f;
#pragma unroll
    for (int e = 0; e < 16; ++e) sum += __expf(v[e] - m);
#pragma unroll
    for (int off = 1; off < 64; off <<= 1) sum += __shfl_xor(sum, off);
    const float inv = 1.0f / sum;

    unsigned long long key[16];
#pragma unroll
    for (int e = 0; e < 16; ++e) {
        const int j = (((e >> 2) * 64 + lane) * 4) + (e & 3);
        unsigned u = __float_as_uint(v[e]);
        u = (u & 0x80000000u) ? ~u : (u | 0x80000000u);
        key[e] = ((unsigned long long)u << 32) | (unsigned)(N - 1 - j);
    }
    unsigned flags = 0;
    for (int it = 0; it < 32; ++it) {
        unsigned long long best = key[0];
#pragma unroll
        for (int e = 1; e < 16; ++e) best = (key[e] > best) ? key[e] : best;
#pragma unroll
        for (int off = 1; off < 64; off <<= 1) {
            const unsigned long long o = __shfl_xor(best, off);
            if (o > best) best = o;
        }
#pragma unroll
        for (int e = 0; e < 16; ++e)
            if (key[e] == best) { flags |= 1u << e; key[e] = 0ull; }
    }
#pragma unroll
    for (int c = 0; c < 4; ++c) {
        float4 o;
        o.x = (flags & (1u << (c * 4 + 0))) ? __expf(v[c * 4 + 0] - m) * inv : 0.f;
        o.y = (flags & (1u << (c * 4 + 1))) ? __expf(v[c * 4 + 1] - m) * inv : 0.f;
        o.z = (flags & (1u << (c * 4 + 2))) ? __expf(v[c * 4 + 2] - m) * inv : 0.f;
        o.w = (flags & (1u << (c * 4 + 3))) ? __expf(v[c * 4 + 3] - m) * inv : 0.f;
        *(float4*)&sr[(c * 64 + lane) * 4] = o;
    }
}

// ---------------- pairwise gelu classifier + 3-way softmax, f16x2 packed over d-pairs ----------------
// 32x32 tile, FULL D=128 resident as halves, single stage, no mid barriers.
// Trans-pipe-minimized gelu: E(x) = w*rsqrt(1+w^2), w = xc*(S+T*u+V*u^2+R*u^3), u=xc^2,
// xc = clamp(x, +-4.5). Coefficients fit to erf(x/sqrt(2)) (max |d gelu| ~4e-4, better
// than the previous tanh-form). All-positive Horner coeffs -> no f16 cancellation.
// 2 trans ops/half2 (v_rsq_f16 x2) vs 4 previously (exp+rcp).
// 0.5 folded into W2; class-2 column subtracted (softmax shift invariance) -> 2 dots not 3.
union H2x4 { uint4 u; __half2 h[4]; };

__device__ __forceinline__ float fdot2_acc(__half2 a, __half2 b, float c) {
#if __has_builtin(__builtin_amdgcn_fdot2)
    typedef _Float16 v2h __attribute__((ext_vector_type(2)));
    union { __half2 h; v2h v; } ua, ub;
    ua.h = a; ub.h = b;
    return __builtin_amdgcn_fdot2(ua.v, ub.v, c, false);
#else
    return fmaf(__low2float(a), __low2float(b),
           fmaf(__high2float(a), __high2float(b), c));
#endif
}

// packed clamp to [-4.5, 4.5]: hip_fp16.h has no __hmin2/__hmax2 on ROCm 7.2 ->
// emit v_pk_max_f16 / v_pk_min_f16 directly (f16 4.5 = 0x4480, -4.5 = 0xC480).
__device__ __forceinline__ __half2 h2clamp45(__half2 x) {
    union { __half2 h; unsigned u; } a, r;
    a.h = x;
    const unsigned lo = 0xC480C480u;   // {-4.5, -4.5}
    const unsigned hi = 0x44804480u;   // {+4.5, +4.5}
    unsigned t;
    asm("v_pk_max_f16 %0, %1, %2" : "=v"(t) : "v"(a.u), "v"(lo));
    asm("v_pk_min_f16 %0, %1, %2" : "=v"(r.u) : "v"(t), "v"(hi));
    return r.h;
}

#define HP 136   // halves pitch: 272 B rows (16B-aligned), bank stride 4 -> only free 2-way alias

__global__ __launch_bounds__(256) void pair_kernel(
    const __half* __restrict__ Ah, const __half* __restrict__ Bh,
    const float* __restrict__ W2, const float* __restrict__ b2,
    float* __restrict__ out)
{
    __shared__ __align__(16) __half AsH[32 * HP];
    __shared__ __align__(16) __half BsH[32 * HP];
    __shared__ __align__(16) __half2 Wh[2][68];
    const int tid = threadIdx.x;
    const int bi = blockIdx.y * 32, bj = blockIdx.x * 32;
    const int tx = tid & 15, ty = tid >> 4;

    // stage A,B (f16) into LDS: 512+512 16B chunks
#pragma unroll
    for (int t = 0; t < 2; ++t) {
        const int e = t * 256 + tid;
        const int row = e >> 4, c = e & 15;
        *(uint4*)&AsH[row * HP + c * 8] = *(const uint4*)&Ah[(size_t)(bi + row) * D + c * 8];
        *(uint4*)&BsH[row * HP + c * 8] = *(const uint4*)&Bh[(size_t)(bj + row) * D + c * 8];
    }
    // W2 -> half2 pairs over d, 0.5 folded, class-2 column subtracted:
    // Wh[cls][dp] = 0.5*{W2[2dp][cls]-W2[2dp][2], W2[2dp+1][cls]-W2[2dp+1][2]}
    if (tid < 128) {
        const int cls = tid >> 6, dp = tid & 63;
        Wh[cls][dp] = __floats2half2_rn(0.5f * (W2[6 * dp + cls]     - W2[6 * dp + 2]),
                                        0.5f * (W2[6 * dp + 3 + cls] - W2[6 * dp + 5]));
    }
    const float bb0 = b2[0] - b2[2], bb1 = b2[1] - b2[2];
    __syncthreads();

    float acc[4][2];                    // [site=ii*2+jj][class 0,1]; class-2 logit == 0
#pragma unroll
    for (int p = 0; p < 4; ++p) { acc[p][0] = bb0; acc[p][1] = bb1; }

    const __half2 ONE = __float2half2_rn(1.0f);
    const __half2 QS  = __float2half2_rn(0.797885f);
    const __half2 QT  = __float2half2_rn(0.122395f);
    const __half2 QV  = __float2half2_rn(0.0120302f);
    const __half2 QR  = __float2half2_rn(0.00197287f);

#pragma unroll 4
    for (int c = 0; c < 16; ++c) {      // 16 chunks x 8 d
        H2x4 a0, a1, b0, b1, w0, w1;
        a0.u = *(const uint4*)&AsH[ty * HP + c * 8];
        a1.u = *(const uint4*)&AsH[(ty + 16) * HP + c * 8];
        b0.u = *(const uint4*)&BsH[tx * HP + c * 8];
        b1.u = *(const uint4*)&BsH[(tx + 16) * HP + c * 8];
        w0.u = *(const uint4*)&Wh[0][c * 4];    // wave-uniform -> LDS broadcast
        w1.u = *(const uint4*)&Wh[1][c * 4];
#pragma unroll
        for (int dp = 0; dp < 4; ++dp) {
            const __half2 aa[2] = { a0.h[dp], a1.h[dp] };
            const __half2 bb[2] = { b0.h[dp], b1.h[dp] };
            const __half2 wc0 = w0.h[dp], wc1 = w1.h[dp];
#pragma unroll
            for (int ii = 0; ii < 2; ++ii)
#pragma unroll
                for (int jj = 0; jj < 2; ++jj) {
                    const __half2 x  = __hadd2(aa[ii], bb[jj]);
                    const __half2 xc = h2clamp45(x);
                    const __half2 u  = __hmul2(xc, xc);
                    __half2 q = __hfma2(QR, u, QV);
                    q = __hfma2(q, u, QT);
                    q = __hfma2(q, u, QS);
                    const __half2 w  = __hmul2(xc, q);
                    const __half2 dn = __hfma2(w, w, ONE);
                    const __half2 rs = h2rsqrt(dn);          // 2x v_rsq_f16 (only trans ops)
                    const __half2 E  = __hmul2(w, rs);       // w/sqrt(1+w^2) ~ erf(x/sqrt2)
                    const __half2 G  = __hfma2(x, E, x);     // x*(1+E) = 2*gelu (0.5 in Wh)
                    float* l = acc[ii * 2 + jj];
                    l[0] = fdot2_acc(G, wc0, l[0]);
                    l[1] = fdot2_acc(G, wc1, l[1]);
                }
        }
    }

#pragma unroll
    for (int ii = 0; ii < 2; ++ii)
#pragma unroll
        for (int jj = 0; jj < 2; ++jj) {
            const int i = bi + ty + 16 * ii;
            const int j = bj + tx + 16 * jj;
            const float* l = acc[ii * 2 + jj];
            const float l0 = l[0], l1 = l[1];                // l2 == 0
            const float mm = fmaxf(fmaxf(l0, l1), 0.f);
            const float e0 = __expf(l0 - mm), e1 = __expf(l1 - mm), e2 = __expf(-mm);
            const float inv2 = 1.0f / (e0 + e1 + e2);
            float* o = out + ((size_t)i * N + j) * 3;
            o[0] = e0 * inv2; o[1] = e1 * inv2; o[2] = e2 * inv2;
        }
}

extern "C" void kernel_launch(void* const* d_in, const int* in_sizes, int n_in,
                              void* d_out, int out_size, void* d_ws, size_t ws_size,
                              hipStream_t stream)
{
    const float* z    = (const float*)d_in[0];
    const float* dist = (const float*)d_in[1];
    const float* Wq   = (const float*)d_in[2];
    const float* bq   = (const float*)d_in[3];
    const float* Wk   = (const float*)d_in[4];
    const float* bk   = (const float*)d_in[5];
    const float* W1   = (const float*)d_in[6];
    const float* b1   = (const float*)d_in[7];
    const float* W2   = (const float*)d_in[8];
    const float* b2   = (const float*)d_in[9];

    float* out = (float*)d_out;
    float* ws  = (float*)d_ws;
    float*  Q  = ws;
    float*  K  = ws + (size_t)N * D;
    __half* Ah = (__half*)(ws + 2 * (size_t)N * D);
    __half* Bh = Ah + (size_t)N * D;

    proj_kernel<<<N / 8, 256, 0, stream>>>(z, Wq, bq, Wk, bk, W1, b1, Q, K, Ah, Bh);
    score_kernel<<<dim3(N / 32, N / 32), 256, 0, stream>>>(Q, K, dist, out);
    topk_kernel<<<N / 4, 256, 0, stream>>>(out);
    pair_kernel<<<dim3(N / 32, N / 32), 256, 0, stream>>>(Ah, Bh, W2, b2, out + (size_t)N * N);
}

// Round 5
// 142.944 us; speedup vs baseline: 1.1228x; 1.1115x over previous
//
#include <hip/hip_runtime.h>
#include <hip/hip_fp16.h>

#define N 1024
#define D 128

// ---------------- proj: Qh,Kh,Ah,Bh (all f16) = z@{Wq,Wk,W1a,W1b} ----------------
// 4 rows/block, 256 blocks -> 1024 waves = 1 wave/SIMD (was 0.5). Scale folded into Qh.
__global__ __launch_bounds__(256) void proj_kernel(
    const float* __restrict__ z,
    const float* __restrict__ Wq, const float* __restrict__ bq,
    const float* __restrict__ Wk, const float* __restrict__ bk,
    const float* __restrict__ W1, const float* __restrict__ b1,
    __half* __restrict__ Qh, __half* __restrict__ Kh,
    __half* __restrict__ Ah, __half* __restrict__ Bh)
{
    const int d  = threadIdx.x & (D - 1);
    const int h  = threadIdx.x >> 7;              // wave-uniform: 0 -> Q/K, 1 -> A/B
    const int r0 = blockIdx.x * 4;
    const float* __restrict__ Wa = h ? W1           : Wq;
    const float* __restrict__ Wb = h ? (W1 + D * D) : Wk;

    float acc0[4] = {0,0,0,0};
    float acc1[4] = {0,0,0,0};

    for (int c = 0; c < D / 4; ++c) {
        float4 zr[4];
#pragma unroll
        for (int r = 0; r < 4; ++r)
            zr[r] = *(const float4*)&z[(r0 + r) * D + c * 4];
#pragma unroll
        for (int q = 0; q < 4; ++q) {
            const int k = c * 4 + q;
            const float wa = Wa[k * D + d];
            const float wb = Wb[k * D + d];
#pragma unroll
            for (int r = 0; r < 4; ++r) {
                const float zv = (q == 0) ? zr[r].x : (q == 1) ? zr[r].y : (q == 2) ? zr[r].z : zr[r].w;
                acc0[r] = fmaf(zv, wa, acc0[r]);
                acc1[r] = fmaf(zv, wb, acc1[r]);
            }
        }
    }
    if (h == 0) {
        const float c0 = bq[d], c1 = bk[d];
        const float scale = 0.08838834764831845f;   // 1/sqrt(128), folded into Qh
#pragma unroll
        for (int r = 0; r < 4; ++r) {
            Qh[(r0 + r) * D + d] = __float2half((acc0[r] + c0) * scale);
            Kh[(r0 + r) * D + d] = __float2half(acc1[r] + c1);
        }
    } else {
        const float c0 = b1[d];
#pragma unroll
        for (int r = 0; r < 4; ++r) {
            Ah[(r0 + r) * D + d] = __float2half(acc0[r] + c0);   // b1 folded
            Bh[(r0 + r) * D + d] = __float2half(acc1[r]);
        }
    }
}

union H2x4 { uint4 u; __half2 h[4]; };

__device__ __forceinline__ float fdot2_acc(__half2 a, __half2 b, float c) {
#if __has_builtin(__builtin_amdgcn_fdot2)
    typedef _Float16 v2h __attribute__((ext_vector_type(2)));
    union { __half2 h; v2h v; } ua, ub;
    ua.h = a; ub.h = b;
    return __builtin_amdgcn_fdot2(ua.v, ub.v, c, false);
#else
    return fmaf(__low2float(a), __low2float(b),
           fmaf(__high2float(a), __high2float(b), c));
#endif
}

#define HP 136   // halves pitch: 272 B rows (16B-aligned); 2-way bank alias only (free)

// ---------------- scores: S = (Qh Kh^T) * exp(-dist), f16 fdot2 (half the instrs/LDS of f32) ----------------
__global__ __launch_bounds__(256) void score_kernel(
    const __half* __restrict__ Qh, const __half* __restrict__ Kh,
    const float* __restrict__ dist, float* __restrict__ S)
{
    __shared__ __align__(16) __half Qs[32 * HP];
    __shared__ __align__(16) __half Ks[32 * HP];
    const int tid = threadIdx.x;
    const int bi = blockIdx.y * 32, bj = blockIdx.x * 32;
    const int tx = tid & 15, ty = tid >> 4;

#pragma unroll
    for (int t = 0; t < 2; ++t) {
        const int e = t * 256 + tid;
        const int row = e >> 4, c = e & 15;
        *(uint4*)&Qs[row * HP + c * 8] = *(const uint4*)&Qh[(size_t)(bi + row) * D + c * 8];
        *(uint4*)&Ks[row * HP + c * 8] = *(const uint4*)&Kh[(size_t)(bj + row) * D + c * 8];
    }
    __syncthreads();

    float a00 = 0.f, a01 = 0.f, a10 = 0.f, a11 = 0.f;

#pragma unroll 4
    for (int c = 0; c < 16; ++c) {      // 16 chunks x 8 dims
        H2x4 q0, q1, k0, k1;
        q0.u = *(const uint4*)&Qs[ty * HP + c * 8];
        q1.u = *(const uint4*)&Qs[(ty + 16) * HP + c * 8];
        k0.u = *(const uint4*)&Ks[tx * HP + c * 8];
        k1.u = *(const uint4*)&Ks[(tx + 16) * HP + c * 8];
#pragma unroll
        for (int dp = 0; dp < 4; ++dp) {
            a00 = fdot2_acc(q0.h[dp], k0.h[dp], a00);
            a01 = fdot2_acc(q0.h[dp], k1.h[dp], a01);
            a10 = fdot2_acc(q1.h[dp], k0.h[dp], a10);
            a11 = fdot2_acc(q1.h[dp], k1.h[dp], a11);
        }
    }

    const int i0 = bi + ty, i1 = bi + ty + 16;
    const int j0 = bj + tx, j1 = bj + tx + 16;
    S[(size_t)i0 * N + j0] = a00 * __expf(-dist[(size_t)i0 * N + j0]);
    S[(size_t)i0 * N + j1] = a01 * __expf(-dist[(size_t)i0 * N + j1]);
    S[(size_t)i1 * N + j0] = a10 * __expf(-dist[(size_t)i1 * N + j0]);
    S[(size_t)i1 * N + j1] = a11 * __expf(-dist[(size_t)i1 * N + j1]);
}

// ---------------- softmax + top-32 per row; one wave per row ----------------
// u32 keys: 22 value bits (monotone f32 map, truncated) + 10-bit index tiebreak (lower j wins,
// matching lax.top_k stability). Accuracy-verified in round 4 (output 0 passed).
__global__ __launch_bounds__(256) void topk_kernel(float* buf)
{
    const int lane = threadIdx.x & 63;
    const int row  = blockIdx.x * 4 + (threadIdx.x >> 6);
    float* sr = buf + (size_t)row * N;

    float v[16];
#pragma unroll
    for (int c = 0; c < 4; ++c) {
        const float4 f = *(const float4*)&sr[(c * 64 + lane) * 4];
        v[c * 4 + 0] = f.x; v[c * 4 + 1] = f.y; v[c * 4 + 2] = f.z; v[c * 4 + 3] = f.w;
    }
    float m = v[0];
#pragma unroll
    for (int e = 1; e < 16; ++e) m = fmaxf(m, v[e]);
#pragma unroll
    for (int off = 1; off < 64; off <<= 1) m = fmaxf(m, __shfl_xor(m, off));
    float sum = 0.f;
#pragma unroll
    for (int e = 0; e < 16; ++e) sum += __expf(v[e] - m);
#pragma unroll
    for (int off = 1; off < 64; off <<= 1) sum += __shfl_xor(sum, off);
    const float inv = 1.0f / sum;

    unsigned key[16];
#pragma unroll
    for (int e = 0; e < 16; ++e) {
        const int j = (((e >> 2) * 64 + lane) * 4) + (e & 3);
        unsigned u = __float_as_uint(v[e]);
        u = (u & 0x80000000u) ? ~u : (u | 0x80000000u);
        key[e] = (u & 0xFFFFFC00u) | (unsigned)(N - 1 - j);
    }
    unsigned flags = 0;
    for (int it = 0; it < 32; ++it) {
        unsigned best = key[0];
#pragma unroll
        for (int e = 1; e < 16; ++e) best = (key[e] > best) ? key[e] : best;
#pragma unroll
        for (int off = 1; off < 64; off <<= 1) {
            const unsigned o = __shfl_xor(best, off);
            if (o > best) best = o;
        }
#pragma unroll
        for (int e = 0; e < 16; ++e)
            if (key[e] == best) { flags |= 1u << e; key[e] = 0u; }
    }
#pragma unroll
    for (int c = 0; c < 4; ++c) {
        float4 o;
        o.x = (flags & (1u << (c * 4 + 0))) ? __expf(v[c * 4 + 0] - m) * inv : 0.f;
        o.y = (flags & (1u << (c * 4 + 1))) ? __expf(v[c * 4 + 1] - m) * inv : 0.f;
        o.z = (flags & (1u << (c * 4 + 2))) ? __expf(v[c * 4 + 2] - m) * inv : 0.f;
        o.w = (flags & (1u << (c * 4 + 3))) ? __expf(v[c * 4 + 3] - m) * inv : 0.f;
        *(float4*)&sr[(c * 64 + lane) * 4] = o;
    }
}

// ---------------- pairwise gelu classifier + 3-way softmax ----------------
// Round-0 sigmoid-form gelu: g = x * sigmoid-ish = gelu(x) DIRECTLY (not 2*gelu!)
// -> Wh carries NO 0.5 factor (round-4 bug: kept the 0.5 from the rsqrt-form, halving logits).
// Class-2 column subtracted (softmax shift invariance) -> 2 dots not 3 (proven round 2).
__global__ __launch_bounds__(256) void pair_kernel(
    const __half* __restrict__ Ah, const __half* __restrict__ Bh,
    const float* __restrict__ W2, const float* __restrict__ b2,
    float* __restrict__ out)
{
    __shared__ __align__(16) __half AsH[32 * HP];
    __shared__ __align__(16) __half BsH[32 * HP];
    __shared__ __align__(16) __half2 Wh[2][68];
    const int tid = threadIdx.x;
    const int bi = blockIdx.y * 32, bj = blockIdx.x * 32;
    const int tx = tid & 15, ty = tid >> 4;

    // stage A,B (f16) into LDS: 512+512 16B chunks
#pragma unroll
    for (int t = 0; t < 2; ++t) {
        const int e = t * 256 + tid;
        const int row = e >> 4, c = e & 15;
        *(uint4*)&AsH[row * HP + c * 8] = *(const uint4*)&Ah[(size_t)(bi + row) * D + c * 8];
        *(uint4*)&BsH[row * HP + c * 8] = *(const uint4*)&Bh[(size_t)(bj + row) * D + c * 8];
    }
    // Wh[cls][dp] = {W2[2dp][cls]-W2[2dp][2], W2[2dp+1][cls]-W2[2dp+1][2]}  (no 0.5!)
    if (tid < 128) {
        const int cls = tid >> 6, dp = tid & 63;
        Wh[cls][dp] = __floats2half2_rn(W2[6 * dp + cls]     - W2[6 * dp + 2],
                                        W2[6 * dp + 3 + cls] - W2[6 * dp + 5]);
    }
    const float bb0 = b2[0] - b2[2], bb1 = b2[1] - b2[2];
    __syncthreads();

    float acc[4][2];                    // [site=ii*2+jj][class 0,1]; class-2 logit == 0
#pragma unroll
    for (int p = 0; p < 4; ++p) { acc[p][0] = bb0; acc[p][1] = bb1; }

    const __half2 C3  = __float2half2_rn(-0.1029434f);
    const __half2 C1  = __float2half2_rn(-2.3022082f);
    const __half2 ONE = __float2half2_rn(1.0f);

#pragma unroll 4
    for (int c = 0; c < 16; ++c) {      // 16 chunks x 8 d
        H2x4 a0, a1, b0, b1, w0, w1;
        a0.u = *(const uint4*)&AsH[ty * HP + c * 8];
        a1.u = *(const uint4*)&AsH[(ty + 16) * HP + c * 8];
        b0.u = *(const uint4*)&BsH[tx * HP + c * 8];
        b1.u = *(const uint4*)&BsH[(tx + 16) * HP + c * 8];
        w0.u = *(const uint4*)&Wh[0][c * 4];    // wave-uniform -> LDS broadcast
        w1.u = *(const uint4*)&Wh[1][c * 4];
#pragma unroll
        for (int dp = 0; dp < 4; ++dp) {
            const __half2 aa[2] = { a0.h[dp], a1.h[dp] };
            const __half2 bb[2] = { b0.h[dp], b1.h[dp] };
            const __half2 wc0 = w0.h[dp], wc1 = w1.h[dp];
#pragma unroll
            for (int ii = 0; ii < 2; ++ii)
#pragma unroll
                for (int jj = 0; jj < 2; ++jj) {
                    const __half2 x = __hadd2(aa[ii], bb[jj]);
                    const __half2 u = __hmul2(x, x);
                    const __half2 p = __hfma2(C3, u, C1);
                    const __half2 t = __hmul2(x, p);
                    const __half2 e = h2exp2(t);          // 2^t ; under/overflow -> 0/inf (correct limits)
                    const __half2 dn = __hadd2(e, ONE);
                    const __half2 r = h2rcp(dn);          // rcp(inf)=0 -> g=0 (correct)
                    const __half2 g = __hmul2(x, r);      // g = gelu(x)
                    float* l = acc[ii * 2 + jj];
                    l[0] = fdot2_acc(g, wc0, l[0]);
                    l[1] = fdot2_acc(g, wc1, l[1]);
                }
        }
    }

#pragma unroll
    for (int ii = 0; ii < 2; ++ii)
#pragma unroll
        for (int jj = 0; jj < 2; ++jj) {
            const int i = bi + ty + 16 * ii;
            const int j = bj + tx + 16 * jj;
            const float* l = acc[ii * 2 + jj];
            const float l0 = l[0], l1 = l[1];                // l2 == 0
            const float mm = fmaxf(fmaxf(l0, l1), 0.f);
            const float e0 = __expf(l0 - mm), e1 = __expf(l1 - mm), e2 = __expf(-mm);
            const float inv2 = 1.0f / (e0 + e1 + e2);
            float* o = out + ((size_t)i * N + j) * 3;
            o[0] = e0 * inv2; o[1] = e1 * inv2; o[2] = e2 * inv2;
        }
}

extern "C" void kernel_launch(void* const* d_in, const int* in_sizes, int n_in,
                              void* d_out, int out_size, void* d_ws, size_t ws_size,
                              hipStream_t stream)
{
    const float* z    = (const float*)d_in[0];
    const float* dist = (const float*)d_in[1];
    const float* Wq   = (const float*)d_in[2];
    const float* bq   = (const float*)d_in[3];
    const float* Wk   = (const float*)d_in[4];
    const float* bk   = (const float*)d_in[5];
    const float* W1   = (const float*)d_in[6];
    const float* b1   = (const float*)d_in[7];
    const float* W2   = (const float*)d_in[8];
    const float* b2   = (const float*)d_in[9];

    float* out = (float*)d_out;
    __half* Qh = (__half*)d_ws;
    __half* Kh = Qh + (size_t)N * D;
    __half* Ah = Kh + (size_t)N * D;
    __half* Bh = Ah + (size_t)N * D;

    proj_kernel<<<N / 4, 256, 0, stream>>>(z, Wq, bq, Wk, bk, W1, b1, Qh, Kh, Ah, Bh);
    score_kernel<<<dim3(N / 32, N / 32), 256, 0, stream>>>(Qh, Kh, dist, out);
    topk_kernel<<<N / 4, 256, 0, stream>>>(out);
    pair_kernel<<<dim3(N / 32, N / 32), 256, 0, stream>>>(Ah, Bh, W2, b2, out + (size_t)N * N);
}